// Round 1
// baseline (6901.151 us; speedup 1.0000x reference)
//
#include <hip/hip_runtime.h>
#include <hip/hip_bf16.h>
#include <cmath>

// ---------------------------------------------------------------------------
// DAFNetBaseLayer — round 0: correctness-first fp32 implementation.
// Shapes: D=512, A=512, H=8, DK=64, HS=4, DKS=64, FF=2048, P=512, E=256, NM=4
// ---------------------------------------------------------------------------

#define DD 512
#define FF 2048
#define PP 512
#define NEG_BIG (-1e30f)

// ---------------- generic tiled fp32 GEMM:  C = act(A[M,K] @ W[K,N] + b) ----
// BM=BN=64, BK=16, 256 threads, 4x4 micro-tile. N % 64 == 0, K % 16 == 0.
__global__ __launch_bounds__(256) void gemm_kernel(
    const float* __restrict__ A, const float* __restrict__ W,
    const float* __restrict__ bias, float* __restrict__ C,
    int M, int N, int K, int relu)
{
    __shared__ float As[16][68];
    __shared__ float Ws[16][68];
    int t  = threadIdx.x;
    int tx = t & 15, ty = t >> 4;
    int bm = blockIdx.x * 64, bn = blockIdx.y * 64;
    float acc[4][4] = {};

    for (int k0 = 0; k0 < K; k0 += 16) {
#pragma unroll
        for (int e = 0; e < 4; ++e) {
            int idx = t + e * 256;          // 0..1023  (64 rows x 16 k)
            int kk = idx & 15, m = idx >> 4;
            int row = bm + m;
            As[kk][m] = (row < M) ? A[(size_t)row * K + k0 + kk] : 0.f;
        }
#pragma unroll
        for (int e = 0; e < 4; ++e) {
            int idx = t + e * 256;          // 16 k x 64 n
            int n = idx & 63, kk = idx >> 6;
            Ws[kk][n] = W[(size_t)(k0 + kk) * N + bn + n];
        }
        __syncthreads();
#pragma unroll
        for (int kk = 0; kk < 16; ++kk) {
            float4 a4 = *(const float4*)&As[kk][ty * 4];
            float4 b4 = *(const float4*)&Ws[kk][tx * 4];
            float av[4] = {a4.x, a4.y, a4.z, a4.w};
            float bv[4] = {b4.x, b4.y, b4.z, b4.w};
#pragma unroll
            for (int i = 0; i < 4; ++i)
#pragma unroll
                for (int j = 0; j < 4; ++j)
                    acc[i][j] += av[i] * bv[j];
        }
        __syncthreads();
    }

#pragma unroll
    for (int i = 0; i < 4; ++i) {
        int row = bm + ty * 4 + i;
        if (row >= M) continue;
        int col = bn + tx * 4;
        float4 bb = *(const float4*)&bias[col];
        float4 r;
        r.x = acc[i][0] + bb.x; r.y = acc[i][1] + bb.y;
        r.z = acc[i][2] + bb.z; r.w = acc[i][3] + bb.w;
        if (relu) {
            r.x = fmaxf(r.x, 0.f); r.y = fmaxf(r.y, 0.f);
            r.z = fmaxf(r.z, 0.f); r.w = fmaxf(r.w, 0.f);
        }
        *(float4*)&C[(size_t)row * N + col] = r;
    }
}

// ---------------- s = h2 @ t2w2 + t2b2  (one wave per row, K=512) ----------
__global__ __launch_bounds__(64) void rowdot512_kernel(
    const float* __restrict__ A, const float* __restrict__ w,
    const float* __restrict__ bptr, float* __restrict__ out)
{
    int row = blockIdx.x;
    int lane = threadIdx.x;
    const float* a = A + (size_t)row * DD;
    float v = 0.f;
#pragma unroll
    for (int i = 0; i < 8; ++i) v += a[lane + 64 * i] * w[lane + 64 * i];
#pragma unroll
    for (int d = 32; d > 0; d >>= 1) v += __shfl_down(v, d, 64);
    if (lane == 0) out[row] = v + bptr[0];
}

// ---------------- segment offsets (serial, E=256) --------------------------
__global__ void seg_offsets_kernel(const int* __restrict__ lens, int* __restrict__ offs, int E)
{
    if (threadIdx.x == 0 && blockIdx.x == 0) {
        int acc = 0;
        for (int g = 0; g < E; ++g) { offs[g] = acc; acc += lens[g]; }
        offs[E] = acc;
    }
}

__global__ void fill_seg_kernel(const int* __restrict__ offs, int* __restrict__ seg)
{
    int g = blockIdx.x;
    int o = offs[g], e = offs[g + 1];
    for (int i = o + threadIdx.x; i < e; i += blockDim.x) seg[i] = g;
}

// ---------------- segment softmax weights (block per group, len<=384) ------
__global__ __launch_bounds__(384) void seg_softmax_kernel(
    const float* __restrict__ s, const int* __restrict__ offs, float* __restrict__ wgt)
{
    __shared__ float red[8];
    int g = blockIdx.x;
    int o = offs[g], len = offs[g + 1] - o;
    int t = threadIdx.x;
    int lane = t & 63, wid = t >> 6;

    float v = (t < len) ? s[o + t] : NEG_BIG;
    float m = v;
#pragma unroll
    for (int d = 32; d > 0; d >>= 1) m = fmaxf(m, __shfl_down(m, d, 64));
    if (lane == 0) red[wid] = m;
    __syncthreads();
    if (t == 0) {
        float mm = red[0];
        for (int i = 1; i < 6; ++i) mm = fmaxf(mm, red[i]);
        red[6] = mm;
    }
    __syncthreads();
    float M = red[6];

    float p = (t < len) ? expf(v - M) : 0.f;
    float sum = p;
#pragma unroll
    for (int d = 32; d > 0; d >>= 1) sum += __shfl_down(sum, d, 64);
    if (lane == 0) red[wid] = sum;
    __syncthreads();
    if (t == 0) {
        float ss = red[0];
        for (int i = 1; i < 6; ++i) ss += red[i];
        red[7] = ss;
    }
    __syncthreads();
    if (t < len) wgt[o + t] = p / red[7];
}

// ---------------- sample_rep = segment_sum(att_x * wgt)  (block per group) -
__global__ __launch_bounds__(256) void seg_wsum_kernel(
    const float* __restrict__ att_x, const float* __restrict__ wgt,
    const int* __restrict__ offs, float* __restrict__ rep)
{
    int g = blockIdx.x;
    int o = offs[g], e = offs[g + 1];
    int c = threadIdx.x;
    float a0 = 0.f, a1 = 0.f;
    for (int i = o; i < e; ++i) {
        float w = wgt[i];
        const float* r = att_x + (size_t)i * DD;
        a0 += r[c] * w;
        a1 += r[c + 256] * w;
    }
    rep[(size_t)g * DD + c] = a0;
    rep[(size_t)g * DD + c + 256] = a1;
}

// ---------------- block reduce helpers (256 threads = 4 waves) -------------
__device__ __forceinline__ float block_sum_256(float v, float* red)
{
    int lane = threadIdx.x & 63, wid = threadIdx.x >> 6;
#pragma unroll
    for (int d = 32; d > 0; d >>= 1) v += __shfl_down(v, d, 64);
    if (lane == 0) red[wid] = v;
    __syncthreads();
    float r = red[0] + red[1] + red[2] + red[3];
    __syncthreads();
    return r;
}

__device__ __forceinline__ float block_max_256(float v, float* red)
{
    int lane = threadIdx.x & 63, wid = threadIdx.x >> 6;
#pragma unroll
    for (int d = 32; d > 0; d >>= 1) v = fmaxf(v, __shfl_down(v, d, 64));
    if (lane == 0) red[wid] = v;
    __syncthreads();
    float r = fmaxf(fmaxf(red[0], red[1]), fmaxf(red[2], red[3]));
    __syncthreads();
    return r;
}

// ---------------- LN1: out = LN(x + att_x*wgt[row]) ------------------------
__global__ __launch_bounds__(256) void ln1_kernel(
    const float* __restrict__ x, const float* __restrict__ att_x,
    const float* __restrict__ wgt, const float* __restrict__ w,
    const float* __restrict__ b, float* __restrict__ out)
{
    __shared__ float red[4];
    size_t row = blockIdx.x;
    int c = threadIdx.x;
    float wr = wgt[row];
    const float* xr = x + row * DD;
    const float* ar = att_x + row * DD;
    float v0 = xr[c] + ar[c] * wr;
    float v1 = xr[c + 256] + ar[c + 256] * wr;
    float mean = block_sum_256(v0 + v1, red) * (1.f / 512.f);
    float d0 = v0 - mean, d1 = v1 - mean;
    float var = block_sum_256(d0 * d0 + d1 * d1, red) * (1.f / 512.f);
    float rstd = rsqrtf(var + 1e-5f);
    out[row * DD + c] = d0 * rstd * w[c] + b[c];
    out[row * DD + c + 256] = d1 * rstd * w[c + 256] + b[c + 256];
}

// ---------------- LN2 (in-place): xb = LN(xb + o[seg[row]]) ----------------
__global__ __launch_bounds__(256) void ln2_kernel(
    float* __restrict__ xb, const float* __restrict__ o,
    const int* __restrict__ seg, const float* __restrict__ w,
    const float* __restrict__ b)
{
    __shared__ float red[4];
    size_t row = blockIdx.x;
    int c = threadIdx.x;
    int g = seg[row];
    const float* orow = o + (size_t)g * DD;
    float v0 = xb[row * DD + c] + orow[c];
    float v1 = xb[row * DD + c + 256] + orow[c + 256];
    float mean = block_sum_256(v0 + v1, red) * (1.f / 512.f);
    float d0 = v0 - mean, d1 = v1 - mean;
    float var = block_sum_256(d0 * d0 + d1 * d1, red) * (1.f / 512.f);
    float rstd = rsqrtf(var + 1e-5f);
    xb[row * DD + c] = d0 * rstd * w[c] + b[c];
    xb[row * DD + c + 256] = d1 * rstd * w[c + 256] + b[c + 256];
}

// ---------------- LN3 + FiLM: out = relu(y*ms+mh) + y, y = LN(xb + ffn) ----
__global__ __launch_bounds__(256) void ln3_film_kernel(
    const float* __restrict__ xb, const float* __restrict__ ffn,
    const int* __restrict__ mode, const float* __restrict__ w,
    const float* __restrict__ b, const float* __restrict__ msc,
    const float* __restrict__ msh, float* __restrict__ out)
{
    __shared__ float red[4];
    size_t row = blockIdx.x;
    int c = threadIdx.x;
    int md = mode[row];
    float v0 = xb[row * DD + c] + ffn[row * DD + c];
    float v1 = xb[row * DD + c + 256] + ffn[row * DD + c + 256];
    float mean = block_sum_256(v0 + v1, red) * (1.f / 512.f);
    float d0 = v0 - mean, d1 = v1 - mean;
    float var = block_sum_256(d0 * d0 + d1 * d1, red) * (1.f / 512.f);
    float rstd = rsqrtf(var + 1e-5f);
    float y0 = d0 * rstd * w[c] + b[c];
    float y1 = d1 * rstd * w[c + 256] + b[c + 256];
    float p0 = y0 * msc[(size_t)md * DD + c] + msh[(size_t)md * DD + c];
    float p1 = y1 * msc[(size_t)md * DD + c + 256] + msh[(size_t)md * DD + c + 256];
    out[row * DD + c] = fmaxf(p0, 0.f) + y0;
    out[row * DD + c + 256] = fmaxf(p1, 0.f) + y1;
}

// ---------------- new_rep = concat(past_rep, sample_rep) -------------------
__global__ void newrep_kernel(const float* __restrict__ past, const float* __restrict__ rep,
                              float* __restrict__ out, int total)
{
    int i = blockIdx.x * blockDim.x + threadIdx.x;
    if (i >= total) return;
    out[i] = (i < PP * DD) ? past[i] : rep[i - PP * DD];
}

// ---------------- outer attention, one block per (q-row, head) -------------
__global__ __launch_bounds__(256) void outer_attn_kernel(
    const float* __restrict__ q, const float* __restrict__ k,
    const float* __restrict__ v, float* __restrict__ o, int PE)
{
    __shared__ float qs[64];
    __shared__ float sc[768];
    __shared__ float red[4];
    __shared__ float part[256];
    int qi = blockIdx.x, h = blockIdx.y;
    int lim = PP + qi;                 // allowed keys j <= lim
    int t = threadIdx.x;

    if (t < 64) qs[t] = q[(size_t)qi * DD + h * 64 + t];
    __syncthreads();

    float lm = NEG_BIG;
    for (int j = t; j < PE; j += 256) {
        float d = NEG_BIG;
        if (j <= lim) {
            const float* kr = k + (size_t)j * DD + h * 64;
            float acc = 0.f;
#pragma unroll
            for (int kk = 0; kk < 64; ++kk) acc += qs[kk] * kr[kk];
            d = acc * 0.125f;
        }
        sc[j] = d;
        lm = fmaxf(lm, d);
    }
    float M = block_max_256(lm, red);

    float ls = 0.f;
    for (int j = t; j < PE; j += 256) {
        float p = (j <= lim) ? expf(sc[j] - M) : 0.f;
        sc[j] = p;
        ls += p;
    }
    float S = block_sum_256(ls, red);
    __syncthreads();                 // sc[] writes visible to all readers
    float inv = 1.f / S;

    int d = t & 63, qtr = t >> 6;
    int jb = PE / 4;
    float acc = 0.f;
    for (int j = qtr * jb; j < qtr * jb + jb; ++j)
        acc += sc[j] * v[(size_t)j * DD + h * 64 + d];
    part[t] = acc;
    __syncthreads();
    if (qtr == 0)
        o[(size_t)qi * DD + h * 64 + d] =
            (part[d] + part[d + 64] + part[d + 128] + part[d + 192]) * inv;
}

// ---------------- score attention: u[i] = mean_h softmax(...)[P+i] ---------
__global__ __launch_bounds__(256) void score_attn_kernel(
    const float* __restrict__ q2, const float* __restrict__ k2,
    float* __restrict__ u, int PE)
{
    __shared__ float qs[256];
    __shared__ float red[4];
    __shared__ float numsh;
    int i = blockIdx.x;
    int lim = PP + i;
    int t = threadIdx.x;
    qs[t] = q2[(size_t)i * 256 + t];
    __syncthreads();

    float usum = 0.f;
    for (int h = 0; h < 4; ++h) {
        float scl[3];
        float lm = NEG_BIG;
#pragma unroll
        for (int c = 0; c < 3; ++c) {
            int j = t + c * 256;
            float d = NEG_BIG;
            if (j < PE && j <= lim) {
                const float* kr = k2 + (size_t)j * 256 + h * 64;
                const float* qh = qs + h * 64;
                float acc = 0.f;
#pragma unroll
                for (int kk = 0; kk < 64; ++kk) acc += qh[kk] * kr[kk];
                d = acc * 0.125f;
            }
            scl[c] = d;
            lm = fmaxf(lm, d);
        }
        float M = block_max_256(lm, red);
        float ls = 0.f;
#pragma unroll
        for (int c = 0; c < 3; ++c) {
            int j = t + c * 256;
            float p = (j < PE && j <= lim) ? expf(scl[c] - M) : 0.f;
            if (j == lim) numsh = p;
            ls += p;
        }
        float S = block_sum_256(ls, red);
        usum += numsh / S;
        __syncthreads();            // protect numsh/red for next head
    }
    if (t == 0) u[i] = usum * 0.25f;
}

// ---------------- cumprod finalize (serial, E=256) -------------------------
__global__ void finalize_kernel(const float* __restrict__ u, float* __restrict__ out_past,
                                float* __restrict__ out_us, int E)
{
    if (threadIdx.x == 0 && blockIdx.x == 0) {
        out_us[E - 1] = u[E - 1];
        float pf = 1.f;                       // pflip[i+1], starts at pflip[E]=1
        for (int i = E - 1; i >= 0; --i) {
            if (i < E - 1) out_us[i] = u[i] * pf;
            pf = (1.f - u[i]) * pf;           // pf becomes pflip[i]
        }
        out_past[0] = pf;                     // pflip[0]
    }
}

// ---------------------------------------------------------------------------
extern "C" void kernel_launch(void* const* d_in, const int* in_sizes, int n_in,
                              void* d_out, int out_size, void* d_ws, size_t ws_size,
                              hipStream_t stream)
{
    const float* x    = (const float*)d_in[0];
    const float* past = (const float*)d_in[1];
    const int*   lens = (const int*)d_in[2];
    const int*   mode = (const int*)d_in[3];
    const float* t1w1 = (const float*)d_in[4];
    const float* t1b1 = (const float*)d_in[5];
    const float* t1w2 = (const float*)d_in[6];
    const float* t1b2 = (const float*)d_in[7];
    const float* t2w1 = (const float*)d_in[8];
    const float* t2b1 = (const float*)d_in[9];
    const float* t2w2 = (const float*)d_in[10];
    const float* t2b2 = (const float*)d_in[11];
    const float* oq_w = (const float*)d_in[12];
    const float* oq_b = (const float*)d_in[13];
    const float* ok_w = (const float*)d_in[14];
    const float* ok_b = (const float*)d_in[15];
    const float* ov_w = (const float*)d_in[16];
    const float* ov_b = (const float*)d_in[17];
    const float* oo_w = (const float*)d_in[18];
    const float* oo_b = (const float*)d_in[19];
    const float* sq_w = (const float*)d_in[20];
    const float* sq_b = (const float*)d_in[21];
    const float* sk_w = (const float*)d_in[22];
    const float* sk_b = (const float*)d_in[23];
    const float* f1w  = (const float*)d_in[24];
    const float* f1b  = (const float*)d_in[25];
    const float* f2w  = (const float*)d_in[26];
    const float* f2b  = (const float*)d_in[27];
    const float* ln1w = (const float*)d_in[28];
    const float* ln1b = (const float*)d_in[29];
    const float* ln2w = (const float*)d_in[30];
    const float* ln2b = (const float*)d_in[31];
    const float* ln3w = (const float*)d_in[32];
    const float* ln3b = (const float*)d_in[33];
    const float* msc  = (const float*)d_in[34];
    const float* msh  = (const float*)d_in[35];

    int N  = in_sizes[0] / DD;
    int E  = in_sizes[2];           // 256
    int PE = PP + E;                // 768
    if (N <= 0) return;

    float* out        = (float*)d_out;
    float* out_x      = out;                          // [N,512] — running activation buf
    float* out_past   = out + (size_t)N * DD;         // [1]
    float* out_us     = out_past + 1;                 // [E]
    float* out_newrep = out_us + E;                   // [768,512]

    // ---- workspace layout (floats) ----
    const int CH = 16384;                             // FFN row-chunk
    size_t hbuf_elems = (size_t)N * DD;
    size_t ffn_elems  = (size_t)CH * FF;
    if (ffn_elems > hbuf_elems) hbuf_elems = ffn_elems;

    float* wsf   = (float*)d_ws;
    float* att_x = wsf;                 wsf += (size_t)N * DD;
    float* hbuf  = wsf;                 wsf += hbuf_elems;
    float* sbuf  = wsf;                 wsf += N;
    float* wgt   = wsf;                 wsf += N;
    float* rep   = wsf;                 wsf += (size_t)E * DD;
    float* qb    = wsf;                 wsf += (size_t)E * DD;
    float* kb    = wsf;                 wsf += (size_t)PE * DD;
    float* vb    = wsf;                 wsf += (size_t)PE * DD;
    float* ob    = wsf;                 wsf += (size_t)E * DD;
    float* q2b   = wsf;                 wsf += (size_t)E * 256;
    float* k2b   = wsf;                 wsf += (size_t)PE * 256;
    float* ub    = wsf;                 wsf += E;
    int*   seg   = (int*)wsf;           wsf += N;
    int*   offs  = (int*)wsf;

    int mg = (N + 63) / 64;

    // ---- inner attention MLPs ----
    gemm_kernel<<<dim3(mg, 8), 256, 0, stream>>>(x,     t1w1, t1b1, hbuf,  N, DD, DD, 1);
    gemm_kernel<<<dim3(mg, 8), 256, 0, stream>>>(hbuf,  t1w2, t1b2, att_x, N, DD, DD, 0);
    gemm_kernel<<<dim3(mg, 8), 256, 0, stream>>>(att_x, t2w1, t2b1, hbuf,  N, DD, DD, 1);
    rowdot512_kernel<<<N, 64, 0, stream>>>(hbuf, t2w2, t2b2, sbuf);

    // ---- segment mapping + softmax ----
    seg_offsets_kernel<<<1, 64, 0, stream>>>(lens, offs, E);
    fill_seg_kernel<<<E, 256, 0, stream>>>(offs, seg);
    seg_softmax_kernel<<<E, 384, 0, stream>>>(sbuf, offs, wgt);
    seg_wsum_kernel<<<E, 256, 0, stream>>>(att_x, wgt, offs, rep);
    ln1_kernel<<<N, 256, 0, stream>>>(x, att_x, wgt, ln1w, ln1b, out_x);

    // ---- new_rep output ----
    int nr_total = PE * DD;
    newrep_kernel<<<(nr_total + 255) / 256, 256, 0, stream>>>(past, rep, out_newrep, nr_total);

    // ---- outer attention ----
    gemm_kernel<<<dim3(E / 64, 8), 256, 0, stream>>>(rep,        oq_w, oq_b, qb, E,  DD, DD, 0);
    gemm_kernel<<<dim3(PE / 64, 8), 256, 0, stream>>>(out_newrep, ok_w, ok_b, kb, PE, DD, DD, 0);
    gemm_kernel<<<dim3(PE / 64, 8), 256, 0, stream>>>(out_newrep, ov_w, ov_b, vb, PE, DD, DD, 0);
    outer_attn_kernel<<<dim3(E, 8), 256, 0, stream>>>(qb, kb, vb, ob, PE);
    gemm_kernel<<<dim3(E / 64, 8), 256, 0, stream>>>(ob, oo_w, oo_b, qb, E, DD, DD, 0); // qb = o-proj
    ln2_kernel<<<N, 256, 0, stream>>>(out_x, qb, seg, ln2w, ln2b);

    // ---- outer score attention ----
    gemm_kernel<<<dim3(E / 64, 4), 256, 0, stream>>>(rep,        sq_w, sq_b, q2b, E,  DD, 256, 0);
    gemm_kernel<<<dim3(PE / 64, 4), 256, 0, stream>>>(out_newrep, sk_w, sk_b, k2b, PE, DD, 256, 0);
    score_attn_kernel<<<E, 256, 0, stream>>>(q2b, k2b, ub, PE);
    finalize_kernel<<<1, 64, 0, stream>>>(ub, out_past, out_us, E);

    // ---- FFN (chunked over rows to bound workspace) ----
    for (int r0 = 0; r0 < N; r0 += CH) {
        int mr = N - r0; if (mr > CH) mr = CH;
        int mgc = (mr + 63) / 64;
        gemm_kernel<<<dim3(mgc, FF / 64), 256, 0, stream>>>(out_x + (size_t)r0 * DD, f1w, f1b, hbuf, mr, FF, DD, 1);
        gemm_kernel<<<dim3(mgc, DD / 64), 256, 0, stream>>>(hbuf, f2w, f2b, att_x + (size_t)r0 * DD, mr, DD, FF, 0);
    }
    ln3_film_kernel<<<N, 256, 0, stream>>>(out_x, att_x, mode, ln3w, ln3b, msc, msh, out_x);
}

// Round 2
// 2120.678 us; speedup vs baseline: 3.2542x; 3.2542x over previous
//
#include <hip/hip_runtime.h>
#include <hip/hip_bf16.h>
#include <cmath>

// ---------------------------------------------------------------------------
// DAFNetBaseLayer — round 2: big GEMMs -> bf16 MFMA (m97 structure),
// small ops stay fp32.  D=512, H=8, DK=64, HS=4, FF=2048, P=512, E=256
// ---------------------------------------------------------------------------

#define DD 512
#define FF 2048
#define PP 512
#define NEG_BIG (-1e30f)

typedef __attribute__((ext_vector_type(8))) short shortx8;   // 8 bf16 = 4 VGPR
typedef __attribute__((ext_vector_type(4))) float floatx4;

__device__ __forceinline__ unsigned short f2b(float f) {
    unsigned int u = __float_as_uint(f);
    unsigned int r = (u + 0x7fffu + ((u >> 16) & 1u)) >> 16;
    return (unsigned short)r;
}
__device__ __forceinline__ float b2f(unsigned short h) {
    return __uint_as_float(((unsigned int)h) << 16);
}

__device__ __forceinline__ void async_copy16(const void* g, void* l) {
    __builtin_amdgcn_global_load_lds(
        (const __attribute__((address_space(1))) unsigned int*)g,
        (__attribute__((address_space(3))) unsigned int*)l, 16, 0, 0);
}

// ---------------- bf16 MFMA GEMM:  C[M,N] = act(A[M,K] @ Bt[N,K]^T + bias) --
// 128x128 tile, BK=32, 256 threads = 4 waves (2x2 of 64x64), 16x16x32 MFMA.
// N % 128 == 0, K % 32 == 0. A,Bt bf16 row-major; bias fp32; C fp32 or bf16.
template<int OUT_BF16, int RELU>
__global__ __launch_bounds__(256) void gemm_bf16_kernel(
    const unsigned short* __restrict__ A, const unsigned short* __restrict__ Bt,
    const float* __restrict__ bias, void* __restrict__ C,
    int M, int N, int K)
{
    __shared__ unsigned short As[128 * 32];
    __shared__ unsigned short Bs[128 * 32];

    int t = threadIdx.x;
    int w = t >> 6, l = t & 63;
    int bm = blockIdx.x * 128, bn = blockIdx.y * 128;
    int wm = (w >> 1) * 64, wn = (w & 1) * 64;

    floatx4 acc[4][4];
#pragma unroll
    for (int i = 0; i < 4; ++i)
#pragma unroll
        for (int j = 0; j < 4; ++j)
#pragma unroll
            for (int r = 0; r < 4; ++r) acc[i][j][r] = 0.f;

    // staging: slot s in [0,512) covers (row = s>>2, kgroup = s&3) of a 128x32 tile
    int s0 = t, s1 = 256 + t;
    int ar0 = s0 >> 2, ak0 = (s0 & 3) * 8;
    int ar1 = s1 >> 2, ak1 = (s1 & 3) * 8;
    int am0 = min(bm + ar0, M - 1);
    int am1 = min(bm + ar1, M - 1);
    const unsigned short* Ap0 = A + (size_t)am0 * K + ak0;
    const unsigned short* Ap1 = A + (size_t)am1 * K + ak1;
    const unsigned short* Bp0 = Bt + (size_t)(bn + ar0) * K + ak0;
    const unsigned short* Bp1 = Bt + (size_t)(bn + ar1) * K + ak1;

    // wave-uniform LDS bases (HW adds lane*16 bytes)
    unsigned short* AsB0 = As + (size_t)(w * 64) * 8;
    unsigned short* AsB1 = As + (size_t)(256 + w * 64) * 8;
    unsigned short* BsB0 = Bs + (size_t)(w * 64) * 8;
    unsigned short* BsB1 = Bs + (size_t)(256 + w * 64) * 8;

    // fragment read offsets (elements); A-op layout: m=lane&15, k=(lane>>4)*8+j
    int fr = l & 15, fq = l >> 4;
    int aoff = (wm + fr) * 32 + fq * 8;
    int boff = (wn + fr) * 32 + fq * 8;

    for (int k0 = 0; k0 < K; k0 += 32) {
        async_copy16(Ap0 + k0, AsB0);
        async_copy16(Ap1 + k0, AsB1);
        async_copy16(Bp0 + k0, BsB0);
        async_copy16(Bp1 + k0, BsB1);
        __syncthreads();

        shortx8 af[4], bf[4];
#pragma unroll
        for (int i = 0; i < 4; ++i) af[i] = *(const shortx8*)&As[aoff + i * 16 * 32];
#pragma unroll
        for (int j = 0; j < 4; ++j) bf[j] = *(const shortx8*)&Bs[boff + j * 16 * 32];
#pragma unroll
        for (int i = 0; i < 4; ++i)
#pragma unroll
            for (int j = 0; j < 4; ++j)
                acc[i][j] = __builtin_amdgcn_mfma_f32_16x16x32_bf16(af[i], bf[j], acc[i][j], 0, 0, 0);
        __syncthreads();
    }

    // epilogue: C row = bm+wm+i*16+fq*4+r, col = bn+wn+j*16+fr
#pragma unroll
    for (int j = 0; j < 4; ++j) {
        int col = bn + wn + j * 16 + fr;
        float bj = bias[col];
#pragma unroll
        for (int i = 0; i < 4; ++i) {
            int row0 = bm + wm + i * 16 + fq * 4;
#pragma unroll
            for (int r = 0; r < 4; ++r) {
                int row = row0 + r;
                if (row >= M) continue;
                float v = acc[i][j][r] + bj;
                if (RELU) v = fmaxf(v, 0.f);
                if (OUT_BF16) ((unsigned short*)C)[(size_t)row * N + col] = f2b(v);
                else          ((float*)C)[(size_t)row * N + col] = v;
            }
        }
    }
}

// ---------------- fp32 -> bf16 elementwise (n % 4 == 0) --------------------
__global__ void cvt_b16_kernel(const float* __restrict__ in, unsigned short* __restrict__ out, size_t n4)
{
    size_t i = (size_t)blockIdx.x * blockDim.x + threadIdx.x;
    if (i >= n4) return;
    float4 v = ((const float4*)in)[i];
    ushort4 o;
    o.x = f2b(v.x); o.y = f2b(v.y); o.z = f2b(v.z); o.w = f2b(v.w);
    ((ushort4*)out)[i] = o;
}

// ---------------- W[K,N] fp32 -> Wt[N,K] bf16 (K,N % 32 == 0) --------------
__global__ __launch_bounds__(256) void transpose_b16_kernel(
    const float* __restrict__ W, unsigned short* __restrict__ Wt, int Kd, int Nd)
{
    __shared__ float tile[32][33];
    int bx = blockIdx.x * 32;   // N
    int by = blockIdx.y * 32;   // K
    int tx = threadIdx.x & 31, ty = threadIdx.x >> 5;  // 32 x 8
#pragma unroll
    for (int i = 0; i < 32; i += 8)
        tile[ty + i][tx] = W[(size_t)(by + ty + i) * Nd + bx + tx];
    __syncthreads();
#pragma unroll
    for (int i = 0; i < 32; i += 8)
        Wt[(size_t)(bx + ty + i) * Kd + by + tx] = f2b(tile[tx][ty + i]);
}

// ---------------- generic tiled fp32 GEMM (small E-sized mats only) --------
__global__ __launch_bounds__(256) void gemm_kernel(
    const float* __restrict__ A, const float* __restrict__ W,
    const float* __restrict__ bias, float* __restrict__ C,
    int M, int N, int K, int relu)
{
    __shared__ float As[16][68];
    __shared__ float Ws[16][68];
    int t  = threadIdx.x;
    int tx = t & 15, ty = t >> 4;
    int bm = blockIdx.x * 64, bn = blockIdx.y * 64;
    float acc[4][4] = {};

    for (int k0 = 0; k0 < K; k0 += 16) {
#pragma unroll
        for (int e = 0; e < 4; ++e) {
            int idx = t + e * 256;
            int kk = idx & 15, m = idx >> 4;
            int row = bm + m;
            As[kk][m] = (row < M) ? A[(size_t)row * K + k0 + kk] : 0.f;
        }
#pragma unroll
        for (int e = 0; e < 4; ++e) {
            int idx = t + e * 256;
            int n = idx & 63, kk = idx >> 6;
            Ws[kk][n] = W[(size_t)(k0 + kk) * N + bn + n];
        }
        __syncthreads();
#pragma unroll
        for (int kk = 0; kk < 16; ++kk) {
            float4 a4 = *(const float4*)&As[kk][ty * 4];
            float4 b4 = *(const float4*)&Ws[kk][tx * 4];
            float av[4] = {a4.x, a4.y, a4.z, a4.w};
            float bv[4] = {b4.x, b4.y, b4.z, b4.w};
#pragma unroll
            for (int i = 0; i < 4; ++i)
#pragma unroll
                for (int j = 0; j < 4; ++j)
                    acc[i][j] += av[i] * bv[j];
        }
        __syncthreads();
    }

#pragma unroll
    for (int i = 0; i < 4; ++i) {
        int row = bm + ty * 4 + i;
        if (row >= M) continue;
        int col = bn + tx * 4;
        float4 bb = *(const float4*)&bias[col];
        float4 r;
        r.x = acc[i][0] + bb.x; r.y = acc[i][1] + bb.y;
        r.z = acc[i][2] + bb.z; r.w = acc[i][3] + bb.w;
        if (relu) {
            r.x = fmaxf(r.x, 0.f); r.y = fmaxf(r.y, 0.f);
            r.z = fmaxf(r.z, 0.f); r.w = fmaxf(r.w, 0.f);
        }
        *(float4*)&C[(size_t)row * N + col] = r;
    }
}

// ---------------- s = h2(bf16) @ t2w2 + t2b2 (one wave per row) ------------
__global__ __launch_bounds__(64) void rowdot512_b16_kernel(
    const unsigned short* __restrict__ A, const float* __restrict__ w,
    const float* __restrict__ bptr, float* __restrict__ out)
{
    int row = blockIdx.x;
    int lane = threadIdx.x;
    const unsigned short* a = A + (size_t)row * DD;
    float v = 0.f;
#pragma unroll
    for (int i = 0; i < 8; ++i) v += b2f(a[lane + 64 * i]) * w[lane + 64 * i];
#pragma unroll
    for (int d = 32; d > 0; d >>= 1) v += __shfl_down(v, d, 64);
    if (lane == 0) out[row] = v + bptr[0];
}

// ---------------- segment machinery ----------------------------------------
__global__ void seg_offsets_kernel(const int* __restrict__ lens, int* __restrict__ offs, int E)
{
    if (threadIdx.x == 0 && blockIdx.x == 0) {
        int acc = 0;
        for (int g = 0; g < E; ++g) { offs[g] = acc; acc += lens[g]; }
        offs[E] = acc;
    }
}

__global__ void fill_seg_kernel(const int* __restrict__ offs, int* __restrict__ seg)
{
    int g = blockIdx.x;
    int o = offs[g], e = offs[g + 1];
    for (int i = o + threadIdx.x; i < e; i += blockDim.x) seg[i] = g;
}

__global__ __launch_bounds__(384) void seg_softmax_kernel(
    const float* __restrict__ s, const int* __restrict__ offs, float* __restrict__ wgt)
{
    __shared__ float red[8];
    int g = blockIdx.x;
    int o = offs[g], len = offs[g + 1] - o;
    int t = threadIdx.x;
    int lane = t & 63, wid = t >> 6;

    float v = (t < len) ? s[o + t] : NEG_BIG;
    float m = v;
#pragma unroll
    for (int d = 32; d > 0; d >>= 1) m = fmaxf(m, __shfl_down(m, d, 64));
    if (lane == 0) red[wid] = m;
    __syncthreads();
    if (t == 0) {
        float mm = red[0];
        for (int i = 1; i < 6; ++i) mm = fmaxf(mm, red[i]);
        red[6] = mm;
    }
    __syncthreads();
    float M = red[6];

    float p = (t < len) ? expf(v - M) : 0.f;
    float sum = p;
#pragma unroll
    for (int d = 32; d > 0; d >>= 1) sum += __shfl_down(sum, d, 64);
    if (lane == 0) red[wid] = sum;
    __syncthreads();
    if (t == 0) {
        float ss = red[0];
        for (int i = 1; i < 6; ++i) ss += red[i];
        red[7] = ss;
    }
    __syncthreads();
    if (t < len) wgt[o + t] = p / red[7];
}

// ---------------- sample_rep = segment_sum(att_x(bf16) * wgt) --------------
__global__ __launch_bounds__(256) void seg_wsum_kernel(
    const unsigned short* __restrict__ att_x, const float* __restrict__ wgt,
    const int* __restrict__ offs, float* __restrict__ rep)
{
    int g = blockIdx.x;
    int o = offs[g], e = offs[g + 1];
    int c = threadIdx.x;
    float a0 = 0.f, a1 = 0.f;
    for (int i = o; i < e; ++i) {
        float w = wgt[i];
        const unsigned short* r = att_x + (size_t)i * DD;
        a0 += b2f(r[c]) * w;
        a1 += b2f(r[c + 256]) * w;
    }
    rep[(size_t)g * DD + c] = a0;
    rep[(size_t)g * DD + c + 256] = a1;
}

// ---------------- block reduce helpers -------------------------------------
__device__ __forceinline__ float block_sum_256(float v, float* red)
{
    int lane = threadIdx.x & 63, wid = threadIdx.x >> 6;
#pragma unroll
    for (int d = 32; d > 0; d >>= 1) v += __shfl_down(v, d, 64);
    if (lane == 0) red[wid] = v;
    __syncthreads();
    float r = red[0] + red[1] + red[2] + red[3];
    __syncthreads();
    return r;
}

__device__ __forceinline__ float block_max_256(float v, float* red)
{
    int lane = threadIdx.x & 63, wid = threadIdx.x >> 6;
#pragma unroll
    for (int d = 32; d > 0; d >>= 1) v = fmaxf(v, __shfl_down(v, d, 64));
    if (lane == 0) red[wid] = v;
    __syncthreads();
    float r = fmaxf(fmaxf(red[0], red[1]), fmaxf(red[2], red[3]));
    __syncthreads();
    return r;
}

// ---------------- LN1: out = LN(x + att_x(bf16)*wgt[row]) ------------------
__global__ __launch_bounds__(256) void ln1_kernel(
    const float* __restrict__ x, const unsigned short* __restrict__ att_x,
    const float* __restrict__ wgt, const float* __restrict__ w,
    const float* __restrict__ b, float* __restrict__ out)
{
    __shared__ float red[4];
    size_t row = blockIdx.x;
    int c = threadIdx.x;
    float wr = wgt[row];
    const float* xr = x + row * DD;
    const unsigned short* ar = att_x + row * DD;
    float v0 = xr[c] + b2f(ar[c]) * wr;
    float v1 = xr[c + 256] + b2f(ar[c + 256]) * wr;
    float mean = block_sum_256(v0 + v1, red) * (1.f / 512.f);
    float d0 = v0 - mean, d1 = v1 - mean;
    float var = block_sum_256(d0 * d0 + d1 * d1, red) * (1.f / 512.f);
    float rstd = rsqrtf(var + 1e-5f);
    out[row * DD + c] = d0 * rstd * w[c] + b[c];
    out[row * DD + c + 256] = d1 * rstd * w[c + 256] + b[c + 256];
}

// ---------------- LN2 (in-place) + bf16 copy -------------------------------
__global__ __launch_bounds__(256) void ln2_kernel(
    float* __restrict__ xb, const float* __restrict__ o,
    const int* __restrict__ seg, const float* __restrict__ w,
    const float* __restrict__ b, unsigned short* __restrict__ xb16)
{
    __shared__ float red[4];
    size_t row = blockIdx.x;
    int c = threadIdx.x;
    int g = seg[row];
    const float* orow = o + (size_t)g * DD;
    float v0 = xb[row * DD + c] + orow[c];
    float v1 = xb[row * DD + c + 256] + orow[c + 256];
    float mean = block_sum_256(v0 + v1, red) * (1.f / 512.f);
    float d0 = v0 - mean, d1 = v1 - mean;
    float var = block_sum_256(d0 * d0 + d1 * d1, red) * (1.f / 512.f);
    float rstd = rsqrtf(var + 1e-5f);
    float y0 = d0 * rstd * w[c] + b[c];
    float y1 = d1 * rstd * w[c + 256] + b[c + 256];
    xb[row * DD + c] = y0;
    xb[row * DD + c + 256] = y1;
    xb16[row * DD + c] = f2b(y0);
    xb16[row * DD + c + 256] = f2b(y1);
}

// ---------------- LN3 + FiLM (ffn in bf16) ---------------------------------
__global__ __launch_bounds__(256) void ln3_film_kernel(
    const float* __restrict__ xb, const unsigned short* __restrict__ ffn,
    const int* __restrict__ mode, const float* __restrict__ w,
    const float* __restrict__ b, const float* __restrict__ msc,
    const float* __restrict__ msh, float* __restrict__ out)
{
    __shared__ float red[4];
    size_t row = blockIdx.x;
    int c = threadIdx.x;
    int md = mode[row];
    float v0 = xb[row * DD + c] + b2f(ffn[row * DD + c]);
    float v1 = xb[row * DD + c + 256] + b2f(ffn[row * DD + c + 256]);
    float mean = block_sum_256(v0 + v1, red) * (1.f / 512.f);
    float d0 = v0 - mean, d1 = v1 - mean;
    float var = block_sum_256(d0 * d0 + d1 * d1, red) * (1.f / 512.f);
    float rstd = rsqrtf(var + 1e-5f);
    float y0 = d0 * rstd * w[c] + b[c];
    float y1 = d1 * rstd * w[c + 256] + b[c + 256];
    float p0 = y0 * msc[(size_t)md * DD + c] + msh[(size_t)md * DD + c];
    float p1 = y1 * msc[(size_t)md * DD + c + 256] + msh[(size_t)md * DD + c + 256];
    out[row * DD + c] = fmaxf(p0, 0.f) + y0;
    out[row * DD + c + 256] = fmaxf(p1, 0.f) + y1;
}

// ---------------- new_rep = concat(past_rep, sample_rep) -------------------
__global__ void newrep_kernel(const float* __restrict__ past, const float* __restrict__ rep,
                              float* __restrict__ out, int total)
{
    int i = blockIdx.x * blockDim.x + threadIdx.x;
    if (i >= total) return;
    out[i] = (i < PP * DD) ? past[i] : rep[i - PP * DD];
}

// ---------------- outer attention, one block per (q-row, head) -------------
__global__ __launch_bounds__(256) void outer_attn_kernel(
    const float* __restrict__ q, const float* __restrict__ k,
    const float* __restrict__ v, float* __restrict__ o, int PE)
{
    __shared__ float qs[64];
    __shared__ float sc[768];
    __shared__ float red[4];
    __shared__ float part[256];
    int qi = blockIdx.x, h = blockIdx.y;
    int lim = PP + qi;
    int t = threadIdx.x;

    if (t < 64) qs[t] = q[(size_t)qi * DD + h * 64 + t];
    __syncthreads();

    float lm = NEG_BIG;
    for (int j = t; j < PE; j += 256) {
        float d = NEG_BIG;
        if (j <= lim) {
            const float* kr = k + (size_t)j * DD + h * 64;
            float acc = 0.f;
#pragma unroll
            for (int kk = 0; kk < 64; ++kk) acc += qs[kk] * kr[kk];
            d = acc * 0.125f;
        }
        sc[j] = d;
        lm = fmaxf(lm, d);
    }
    float M = block_max_256(lm, red);

    float ls = 0.f;
    for (int j = t; j < PE; j += 256) {
        float p = (j <= lim) ? expf(sc[j] - M) : 0.f;
        sc[j] = p;
        ls += p;
    }
    float S = block_sum_256(ls, red);
    __syncthreads();
    float inv = 1.f / S;

    int d = t & 63, qtr = t >> 6;
    int jb = PE / 4;
    float acc = 0.f;
    for (int j = qtr * jb; j < qtr * jb + jb; ++j)
        acc += sc[j] * v[(size_t)j * DD + h * 64 + d];
    part[t] = acc;
    __syncthreads();
    if (qtr == 0)
        o[(size_t)qi * DD + h * 64 + d] =
            (part[d] + part[d + 64] + part[d + 128] + part[d + 192]) * inv;
}

// ---------------- score attention: u[i] = mean_h softmax(...)[P+i] ---------
__global__ __launch_bounds__(256) void score_attn_kernel(
    const float* __restrict__ q2, const float* __restrict__ k2,
    float* __restrict__ u, int PE)
{
    __shared__ float qs[256];
    __shared__ float red[4];
    __shared__ float numsh;
    int i = blockIdx.x;
    int lim = PP + i;
    int t = threadIdx.x;
    qs[t] = q2[(size_t)i * 256 + t];
    __syncthreads();

    float usum = 0.f;
    for (int h = 0; h < 4; ++h) {
        float scl[3];
        float lm = NEG_BIG;
#pragma unroll
        for (int c = 0; c < 3; ++c) {
            int j = t + c * 256;
            float d = NEG_BIG;
            if (j < PE && j <= lim) {
                const float* kr = k2 + (size_t)j * 256 + h * 64;
                const float* qh = qs + h * 64;
                float acc = 0.f;
#pragma unroll
                for (int kk = 0; kk < 64; ++kk) acc += qh[kk] * kr[kk];
                d = acc * 0.125f;
            }
            scl[c] = d;
            lm = fmaxf(lm, d);
        }
        float M = block_max_256(lm, red);
        float ls = 0.f;
#pragma unroll
        for (int c = 0; c < 3; ++c) {
            int j = t + c * 256;
            float p = (j < PE && j <= lim) ? expf(scl[c] - M) : 0.f;
            if (j == lim) numsh = p;
            ls += p;
        }
        float S = block_sum_256(ls, red);
        usum += numsh / S;
        __syncthreads();
    }
    if (t == 0) u[i] = usum * 0.25f;
}

// ---------------- cumprod finalize -----------------------------------------
__global__ void finalize_kernel(const float* __restrict__ u, float* __restrict__ out_past,
                                float* __restrict__ out_us, int E)
{
    if (threadIdx.x == 0 && blockIdx.x == 0) {
        out_us[E - 1] = u[E - 1];
        float pf = 1.f;
        for (int i = E - 1; i >= 0; --i) {
            if (i < E - 1) out_us[i] = u[i] * pf;
            pf = (1.f - u[i]) * pf;
        }
        out_past[0] = pf;
    }
}

// ---------------------------------------------------------------------------
extern "C" void kernel_launch(void* const* d_in, const int* in_sizes, int n_in,
                              void* d_out, int out_size, void* d_ws, size_t ws_size,
                              hipStream_t stream)
{
    const float* x    = (const float*)d_in[0];
    const float* past = (const float*)d_in[1];
    const int*   lens = (const int*)d_in[2];
    const int*   mode = (const int*)d_in[3];
    const float* t1w1 = (const float*)d_in[4];
    const float* t1b1 = (const float*)d_in[5];
    const float* t1w2 = (const float*)d_in[6];
    const float* t1b2 = (const float*)d_in[7];
    const float* t2w1 = (const float*)d_in[8];
    const float* t2b1 = (const float*)d_in[9];
    const float* t2w2 = (const float*)d_in[10];
    const float* t2b2 = (const float*)d_in[11];
    const float* oq_w = (const float*)d_in[12];
    const float* oq_b = (const float*)d_in[13];
    const float* ok_w = (const float*)d_in[14];
    const float* ok_b = (const float*)d_in[15];
    const float* ov_w = (const float*)d_in[16];
    const float* ov_b = (const float*)d_in[17];
    const float* oo_w = (const float*)d_in[18];
    const float* oo_b = (const float*)d_in[19];
    const float* sq_w = (const float*)d_in[20];
    const float* sq_b = (const float*)d_in[21];
    const float* sk_w = (const float*)d_in[22];
    const float* sk_b = (const float*)d_in[23];
    const float* f1w  = (const float*)d_in[24];
    const float* f1b  = (const float*)d_in[25];
    const float* f2w  = (const float*)d_in[26];
    const float* f2b_ = (const float*)d_in[27];
    const float* ln1w = (const float*)d_in[28];
    const float* ln1b = (const float*)d_in[29];
    const float* ln2w = (const float*)d_in[30];
    const float* ln2b = (const float*)d_in[31];
    const float* ln3w = (const float*)d_in[32];
    const float* ln3b = (const float*)d_in[33];
    const float* msc  = (const float*)d_in[34];
    const float* msh  = (const float*)d_in[35];

    int N  = in_sizes[0] / DD;
    int E  = in_sizes[2];
    int PE = PP + E;
    if (N <= 0) return;

    float* out        = (float*)d_out;
    float* out_x      = out;
    float* out_past   = out + (size_t)N * DD;
    float* out_us     = out_past + 1;
    float* out_newrep = out_us + E;

    // ---- workspace layout ----
    const int CH = 16384;                               // FFN row-chunk
    char* wp = (char*)d_ws;
    unsigned short* b16_a = (unsigned short*)wp;  wp += (size_t)N * DD * 2;      // xb16 -> att_x b16 -> ffn-out b16
    unsigned short* b16_b = (unsigned short*)wp;  wp += (size_t)N * DD * 2;      // h1 -> h2 -> ln2 b16
    unsigned short* ffh   = (unsigned short*)wp;  wp += (size_t)CH * FF * 2;     // f1 chunk out
    unsigned short* wt1   = (unsigned short*)wp;  wp += (size_t)DD * DD * 2;
    unsigned short* wt2   = (unsigned short*)wp;  wp += (size_t)DD * DD * 2;
    unsigned short* wt3   = (unsigned short*)wp;  wp += (size_t)DD * DD * 2;
    unsigned short* wtf1  = (unsigned short*)wp;  wp += (size_t)FF * DD * 2;
    unsigned short* wtf2  = (unsigned short*)wp;  wp += (size_t)DD * FF * 2;
    float* sbuf = (float*)wp;  wp += (size_t)N * 4;
    float* wgt  = (float*)wp;  wp += (size_t)N * 4;
    float* rep  = (float*)wp;  wp += (size_t)E * DD * 4;
    float* qb   = (float*)wp;  wp += (size_t)E * DD * 4;
    float* kb   = (float*)wp;  wp += (size_t)PE * DD * 4;
    float* vb   = (float*)wp;  wp += (size_t)PE * DD * 4;
    float* ob   = (float*)wp;  wp += (size_t)E * DD * 4;
    float* q2b  = (float*)wp;  wp += (size_t)E * 256 * 4;
    float* k2b  = (float*)wp;  wp += (size_t)PE * 256 * 4;
    float* ub   = (float*)wp;  wp += (size_t)E * 4;
    int*   seg  = (int*)wp;    wp += (size_t)N * 4;
    int*   offs = (int*)wp;

    int mg128 = (N + 127) / 128;

    // ---- weight transpose+convert (5 mats, ~12 MB total) ----
    transpose_b16_kernel<<<dim3(DD / 32, DD / 32), 256, 0, stream>>>(t1w1, wt1, DD, DD);
    transpose_b16_kernel<<<dim3(DD / 32, DD / 32), 256, 0, stream>>>(t1w2, wt2, DD, DD);
    transpose_b16_kernel<<<dim3(DD / 32, DD / 32), 256, 0, stream>>>(t2w1, wt3, DD, DD);
    transpose_b16_kernel<<<dim3(FF / 32, DD / 32), 256, 0, stream>>>(f1w, wtf1, DD, FF);
    transpose_b16_kernel<<<dim3(DD / 32, FF / 32), 256, 0, stream>>>(f2w, wtf2, FF, DD);

    // ---- x -> bf16 ----
    size_t n4 = (size_t)N * DD / 4;
    cvt_b16_kernel<<<(int)((n4 + 255) / 256), 256, 0, stream>>>(x, b16_a, n4);

    // ---- inner attention MLPs (bf16 MFMA) ----
    gemm_bf16_kernel<1, 1><<<dim3(mg128, DD / 128), 256, 0, stream>>>(b16_a, wt1, t1b1, b16_b, N, DD, DD);
    gemm_bf16_kernel<1, 0><<<dim3(mg128, DD / 128), 256, 0, stream>>>(b16_b, wt2, t1b2, b16_a, N, DD, DD);
    gemm_bf16_kernel<1, 1><<<dim3(mg128, DD / 128), 256, 0, stream>>>(b16_a, wt3, t2b1, b16_b, N, DD, DD);
    rowdot512_b16_kernel<<<N, 64, 0, stream>>>(b16_b, t2w2, t2b2, sbuf);

    // ---- segment softmax + rep + LN1 ----
    seg_offsets_kernel<<<1, 64, 0, stream>>>(lens, offs, E);
    fill_seg_kernel<<<E, 256, 0, stream>>>(offs, seg);
    seg_softmax_kernel<<<E, 384, 0, stream>>>(sbuf, offs, wgt);
    seg_wsum_kernel<<<E, 256, 0, stream>>>(b16_a, wgt, offs, rep);
    ln1_kernel<<<N, 256, 0, stream>>>(x, b16_a, wgt, ln1w, ln1b, out_x);

    // ---- new_rep output ----
    int nr_total = PE * DD;
    newrep_kernel<<<(nr_total + 255) / 256, 256, 0, stream>>>(past, rep, out_newrep, nr_total);

    // ---- outer attention (fp32, tiny) ----
    gemm_kernel<<<dim3(E / 64, 8), 256, 0, stream>>>(rep,        oq_w, oq_b, qb, E,  DD, DD, 0);
    gemm_kernel<<<dim3(PE / 64, 8), 256, 0, stream>>>(out_newrep, ok_w, ok_b, kb, PE, DD, DD, 0);
    gemm_kernel<<<dim3(PE / 64, 8), 256, 0, stream>>>(out_newrep, ov_w, ov_b, vb, PE, DD, DD, 0);
    outer_attn_kernel<<<dim3(E, 8), 256, 0, stream>>>(qb, kb, vb, ob, PE);
    gemm_kernel<<<dim3(E / 64, 8), 256, 0, stream>>>(ob, oo_w, oo_b, qb, E, DD, DD, 0);
    ln2_kernel<<<N, 256, 0, stream>>>(out_x, qb, seg, ln2w, ln2b, b16_b);

    // ---- outer score attention (fp32, tiny) ----
    gemm_kernel<<<dim3(E / 64, 4), 256, 0, stream>>>(rep,        sq_w, sq_b, q2b, E,  DD, 256, 0);
    gemm_kernel<<<dim3(PE / 64, 4), 256, 0, stream>>>(out_newrep, sk_w, sk_b, k2b, PE, DD, 256, 0);
    score_attn_kernel<<<E, 256, 0, stream>>>(q2b, k2b, ub, PE);
    finalize_kernel<<<1, 64, 0, stream>>>(ub, out_past, out_us, E);

    // ---- FFN (bf16 MFMA, chunked) ----
    for (int r0 = 0; r0 < N; r0 += CH) {
        int mr = N - r0; if (mr > CH) mr = CH;
        int mgc = (mr + 127) / 128;
        gemm_bf16_kernel<1, 1><<<dim3(mgc, FF / 128), 256, 0, stream>>>(
            b16_b + (size_t)r0 * DD, wtf1, f1b, ffh, mr, FF, DD);
        gemm_bf16_kernel<1, 0><<<dim3(mgc, DD / 128), 256, 0, stream>>>(
            ffh, wtf2, f2b_, b16_a + (size_t)r0 * DD, mr, DD, FF);
    }
    ln3_film_kernel<<<N, 256, 0, stream>>>(out_x, b16_a, mode, ln3w, ln3b, msc, msh, out_x);
}

// Round 3
// 1949.932 us; speedup vs baseline: 3.5392x; 1.0876x over previous
//
#include <hip/hip_runtime.h>
#include <hip/hip_bf16.h>
#include <cmath>

// ---------------------------------------------------------------------------
// DAFNetBaseLayer — round 3: coalesced LDS attention + fused projection GEMM.
// D=512, H=8, DK=64, HS=4, FF=2048, P=512, E=256
// ---------------------------------------------------------------------------

#define DD 512
#define FF 2048
#define PP 512
#define NEG_BIG (-1e30f)

typedef __attribute__((ext_vector_type(8))) short shortx8;   // 8 bf16 = 4 VGPR
typedef __attribute__((ext_vector_type(4))) float floatx4;

__device__ __forceinline__ unsigned short f2b(float f) {
    unsigned int u = __float_as_uint(f);
    unsigned int r = (u + 0x7fffu + ((u >> 16) & 1u)) >> 16;
    return (unsigned short)r;
}
__device__ __forceinline__ float b2f(unsigned short h) {
    return __uint_as_float(((unsigned int)h) << 16);
}

__device__ __forceinline__ void async_copy16(const void* g, void* l) {
    __builtin_amdgcn_global_load_lds(
        (const __attribute__((address_space(1))) unsigned int*)g,
        (__attribute__((address_space(3))) unsigned int*)l, 16, 0, 0);
}

// ---------------- bf16 MFMA GEMM:  C[M,N] = act(A[M,K] @ Bt[N,K]^T + bias) --
// 128x128 tile, BK=32, 256 threads = 4 waves (2x2 of 64x64), 16x16x32 MFMA.
// N % 128 == 0, K % 32 == 0. A,Bt bf16 row-major; bias fp32; C fp32 or bf16.
template<int OUT_BF16, int RELU>
__global__ __launch_bounds__(256) void gemm_bf16_kernel(
    const unsigned short* __restrict__ A, const unsigned short* __restrict__ Bt,
    const float* __restrict__ bias, void* __restrict__ C,
    int M, int N, int K)
{
    __shared__ unsigned short As[128 * 32];
    __shared__ unsigned short Bs[128 * 32];

    int t = threadIdx.x;
    int w = t >> 6, l = t & 63;
    int bm = blockIdx.x * 128, bn = blockIdx.y * 128;
    int wm = (w >> 1) * 64, wn = (w & 1) * 64;

    floatx4 acc[4][4];
#pragma unroll
    for (int i = 0; i < 4; ++i)
#pragma unroll
        for (int j = 0; j < 4; ++j)
#pragma unroll
            for (int r = 0; r < 4; ++r) acc[i][j][r] = 0.f;

    int s0 = t, s1 = 256 + t;
    int ar0 = s0 >> 2, ak0 = (s0 & 3) * 8;
    int ar1 = s1 >> 2, ak1 = (s1 & 3) * 8;
    int am0 = min(bm + ar0, M - 1);
    int am1 = min(bm + ar1, M - 1);
    const unsigned short* Ap0 = A + (size_t)am0 * K + ak0;
    const unsigned short* Ap1 = A + (size_t)am1 * K + ak1;
    const unsigned short* Bp0 = Bt + (size_t)(bn + ar0) * K + ak0;
    const unsigned short* Bp1 = Bt + (size_t)(bn + ar1) * K + ak1;

    unsigned short* AsB0 = As + (size_t)(w * 64) * 8;
    unsigned short* AsB1 = As + (size_t)(256 + w * 64) * 8;
    unsigned short* BsB0 = Bs + (size_t)(w * 64) * 8;
    unsigned short* BsB1 = Bs + (size_t)(256 + w * 64) * 8;

    int fr = l & 15, fq = l >> 4;
    int aoff = (wm + fr) * 32 + fq * 8;
    int boff = (wn + fr) * 32 + fq * 8;

    for (int k0 = 0; k0 < K; k0 += 32) {
        async_copy16(Ap0 + k0, AsB0);
        async_copy16(Ap1 + k0, AsB1);
        async_copy16(Bp0 + k0, BsB0);
        async_copy16(Bp1 + k0, BsB1);
        __syncthreads();

        shortx8 af[4], bf[4];
#pragma unroll
        for (int i = 0; i < 4; ++i) af[i] = *(const shortx8*)&As[aoff + i * 16 * 32];
#pragma unroll
        for (int j = 0; j < 4; ++j) bf[j] = *(const shortx8*)&Bs[boff + j * 16 * 32];
#pragma unroll
        for (int i = 0; i < 4; ++i)
#pragma unroll
            for (int j = 0; j < 4; ++j)
                acc[i][j] = __builtin_amdgcn_mfma_f32_16x16x32_bf16(af[i], bf[j], acc[i][j], 0, 0, 0);
        __syncthreads();
    }

#pragma unroll
    for (int j = 0; j < 4; ++j) {
        int col = bn + wn + j * 16 + fr;
        float bj = bias[col];
#pragma unroll
        for (int i = 0; i < 4; ++i) {
            int row0 = bm + wm + i * 16 + fq * 4;
#pragma unroll
            for (int r = 0; r < 4; ++r) {
                int row = row0 + r;
                if (row >= M) continue;
                float v = acc[i][j][r] + bj;
                if (RELU) v = fmaxf(v, 0.f);
                if (OUT_BF16) ((unsigned short*)C)[(size_t)row * N + col] = f2b(v);
                else          ((float*)C)[(size_t)row * N + col] = v;
            }
        }
    }
}

// ---------------- fp32 -> bf16 elementwise (n % 4 == 0) --------------------
__global__ void cvt_b16_kernel(const float* __restrict__ in, unsigned short* __restrict__ out, size_t n4)
{
    size_t i = (size_t)blockIdx.x * blockDim.x + threadIdx.x;
    if (i >= n4) return;
    float4 v = ((const float4*)in)[i];
    ushort4 o;
    o.x = f2b(v.x); o.y = f2b(v.y); o.z = f2b(v.z); o.w = f2b(v.w);
    ((ushort4*)out)[i] = o;
}

// ---------------- W[K,N] fp32 -> Wt[N,K] bf16 (K,N % 32 == 0) --------------
__global__ __launch_bounds__(256) void transpose_b16_kernel(
    const float* __restrict__ W, unsigned short* __restrict__ Wt, int Kd, int Nd)
{
    __shared__ float tile[32][33];
    int bx = blockIdx.x * 32;   // N
    int by = blockIdx.y * 32;   // K
    int tx = threadIdx.x & 31, ty = threadIdx.x >> 5;  // 32 x 8
#pragma unroll
    for (int i = 0; i < 32; i += 8)
        tile[ty + i][tx] = W[(size_t)(by + ty + i) * Nd + bx + tx];
    __syncthreads();
#pragma unroll
    for (int i = 0; i < 32; i += 8)
        Wt[(size_t)(bx + ty + i) * Kd + by + tx] = f2b(tile[tx][ty + i]);
}

// ---------------- bias concat for fused projection -------------------------
__global__ void bcat_kernel(const float* __restrict__ okb, const float* __restrict__ ovb,
                            const float* __restrict__ oqb, const float* __restrict__ skb,
                            const float* __restrict__ sqb, float* __restrict__ bcat)
{
    int i = blockIdx.x * 256 + threadIdx.x;  // 0..2047
    float v;
    if      (i < 512)  v = okb[i];
    else if (i < 1024) v = ovb[i - 512];
    else if (i < 1536) v = oqb[i - 1024];
    else if (i < 1792) v = skb[i - 1536];
    else               v = sqb[i - 1792];
    bcat[i] = v;
}

// ---------------- generic tiled fp32 GEMM (o-proj only) --------------------
__global__ __launch_bounds__(256) void gemm_kernel(
    const float* __restrict__ A, const float* __restrict__ W,
    const float* __restrict__ bias, float* __restrict__ C,
    int M, int N, int K, int relu)
{
    __shared__ float As[16][68];
    __shared__ float Ws[16][68];
    int t  = threadIdx.x;
    int tx = t & 15, ty = t >> 4;
    int bm = blockIdx.x * 64, bn = blockIdx.y * 64;
    float acc[4][4] = {};

    for (int k0 = 0; k0 < K; k0 += 16) {
#pragma unroll
        for (int e = 0; e < 4; ++e) {
            int idx = t + e * 256;
            int kk = idx & 15, m = idx >> 4;
            int row = bm + m;
            As[kk][m] = (row < M) ? A[(size_t)row * K + k0 + kk] : 0.f;
        }
#pragma unroll
        for (int e = 0; e < 4; ++e) {
            int idx = t + e * 256;
            int n = idx & 63, kk = idx >> 6;
            Ws[kk][n] = W[(size_t)(k0 + kk) * N + bn + n];
        }
        __syncthreads();
#pragma unroll
        for (int kk = 0; kk < 16; ++kk) {
            float4 a4 = *(const float4*)&As[kk][ty * 4];
            float4 b4 = *(const float4*)&Ws[kk][tx * 4];
            float av[4] = {a4.x, a4.y, a4.z, a4.w};
            float bv[4] = {b4.x, b4.y, b4.z, b4.w};
#pragma unroll
            for (int i = 0; i < 4; ++i)
#pragma unroll
                for (int j = 0; j < 4; ++j)
                    acc[i][j] += av[i] * bv[j];
        }
        __syncthreads();
    }

#pragma unroll
    for (int i = 0; i < 4; ++i) {
        int row = bm + ty * 4 + i;
        if (row >= M) continue;
        int col = bn + tx * 4;
        float4 bb = *(const float4*)&bias[col];
        float4 r;
        r.x = acc[i][0] + bb.x; r.y = acc[i][1] + bb.y;
        r.z = acc[i][2] + bb.z; r.w = acc[i][3] + bb.w;
        if (relu) {
            r.x = fmaxf(r.x, 0.f); r.y = fmaxf(r.y, 0.f);
            r.z = fmaxf(r.z, 0.f); r.w = fmaxf(r.w, 0.f);
        }
        *(float4*)&C[(size_t)row * N + col] = r;
    }
}

// ---------------- s = h2(bf16) @ t2w2 + t2b2 (one wave per row) ------------
__global__ __launch_bounds__(64) void rowdot512_b16_kernel(
    const unsigned short* __restrict__ A, const float* __restrict__ w,
    const float* __restrict__ bptr, float* __restrict__ out)
{
    int row = blockIdx.x;
    int lane = threadIdx.x;
    const unsigned short* a = A + (size_t)row * DD;
    float v = 0.f;
#pragma unroll
    for (int i = 0; i < 8; ++i) v += b2f(a[lane + 64 * i]) * w[lane + 64 * i];
#pragma unroll
    for (int d = 32; d > 0; d >>= 1) v += __shfl_down(v, d, 64);
    if (lane == 0) out[row] = v + bptr[0];
}

// ---------------- segment machinery ----------------------------------------
__global__ void seg_offsets_kernel(const int* __restrict__ lens, int* __restrict__ offs, int E)
{
    if (threadIdx.x == 0 && blockIdx.x == 0) {
        int acc = 0;
        for (int g = 0; g < E; ++g) { offs[g] = acc; acc += lens[g]; }
        offs[E] = acc;
    }
}

__global__ void fill_seg_kernel(const int* __restrict__ offs, int* __restrict__ seg)
{
    int g = blockIdx.x;
    int o = offs[g], e = offs[g + 1];
    for (int i = o + threadIdx.x; i < e; i += blockDim.x) seg[i] = g;
}

__global__ __launch_bounds__(384) void seg_softmax_kernel(
    const float* __restrict__ s, const int* __restrict__ offs, float* __restrict__ wgt)
{
    __shared__ float red[8];
    int g = blockIdx.x;
    int o = offs[g], len = offs[g + 1] - o;
    int t = threadIdx.x;
    int lane = t & 63, wid = t >> 6;

    float v = (t < len) ? s[o + t] : NEG_BIG;
    float m = v;
#pragma unroll
    for (int d = 32; d > 0; d >>= 1) m = fmaxf(m, __shfl_down(m, d, 64));
    if (lane == 0) red[wid] = m;
    __syncthreads();
    if (t == 0) {
        float mm = red[0];
        for (int i = 1; i < 6; ++i) mm = fmaxf(mm, red[i]);
        red[6] = mm;
    }
    __syncthreads();
    float M = red[6];

    float p = (t < len) ? expf(v - M) : 0.f;
    float sum = p;
#pragma unroll
    for (int d = 32; d > 0; d >>= 1) sum += __shfl_down(sum, d, 64);
    if (lane == 0) red[wid] = sum;
    __syncthreads();
    if (t == 0) {
        float ss = red[0];
        for (int i = 1; i < 6; ++i) ss += red[i];
        red[7] = ss;
    }
    __syncthreads();
    if (t < len) wgt[o + t] = p / red[7];
}

__global__ __launch_bounds__(256) void seg_wsum_kernel(
    const unsigned short* __restrict__ att_x, const float* __restrict__ wgt,
    const int* __restrict__ offs, float* __restrict__ rep)
{
    int g = blockIdx.x;
    int o = offs[g], e = offs[g + 1];
    int c = threadIdx.x;
    float a0 = 0.f, a1 = 0.f;
    for (int i = o; i < e; ++i) {
        float w = wgt[i];
        const unsigned short* r = att_x + (size_t)i * DD;
        a0 += b2f(r[c]) * w;
        a1 += b2f(r[c + 256]) * w;
    }
    rep[(size_t)g * DD + c] = a0;
    rep[(size_t)g * DD + c + 256] = a1;
}

// ---------------- block reduce helpers -------------------------------------
__device__ __forceinline__ float block_sum_256(float v, float* red)
{
    int lane = threadIdx.x & 63, wid = threadIdx.x >> 6;
#pragma unroll
    for (int d = 32; d > 0; d >>= 1) v += __shfl_down(v, d, 64);
    if (lane == 0) red[wid] = v;
    __syncthreads();
    float r = red[0] + red[1] + red[2] + red[3];
    __syncthreads();
    return r;
}

// ---------------- LN1: out = LN(x + att_x(bf16)*wgt[row]) ------------------
__global__ __launch_bounds__(256) void ln1_kernel(
    const float* __restrict__ x, const unsigned short* __restrict__ att_x,
    const float* __restrict__ wgt, const float* __restrict__ w,
    const float* __restrict__ b, float* __restrict__ out)
{
    __shared__ float red[4];
    size_t row = blockIdx.x;
    int c = threadIdx.x;
    float wr = wgt[row];
    const float* xr = x + row * DD;
    const unsigned short* ar = att_x + row * DD;
    float v0 = xr[c] + b2f(ar[c]) * wr;
    float v1 = xr[c + 256] + b2f(ar[c + 256]) * wr;
    float mean = block_sum_256(v0 + v1, red) * (1.f / 512.f);
    float d0 = v0 - mean, d1 = v1 - mean;
    float var = block_sum_256(d0 * d0 + d1 * d1, red) * (1.f / 512.f);
    float rstd = rsqrtf(var + 1e-5f);
    out[row * DD + c] = d0 * rstd * w[c] + b[c];
    out[row * DD + c + 256] = d1 * rstd * w[c + 256] + b[c + 256];
}

// ---------------- LN2 (in-place) + bf16 copy -------------------------------
__global__ __launch_bounds__(256) void ln2_kernel(
    float* __restrict__ xb, const float* __restrict__ o,
    const int* __restrict__ seg, const float* __restrict__ w,
    const float* __restrict__ b, unsigned short* __restrict__ xb16)
{
    __shared__ float red[4];
    size_t row = blockIdx.x;
    int c = threadIdx.x;
    int g = seg[row];
    const float* orow = o + (size_t)g * DD;
    float v0 = xb[row * DD + c] + orow[c];
    float v1 = xb[row * DD + c + 256] + orow[c + 256];
    float mean = block_sum_256(v0 + v1, red) * (1.f / 512.f);
    float d0 = v0 - mean, d1 = v1 - mean;
    float var = block_sum_256(d0 * d0 + d1 * d1, red) * (1.f / 512.f);
    float rstd = rsqrtf(var + 1e-5f);
    float y0 = d0 * rstd * w[c] + b[c];
    float y1 = d1 * rstd * w[c + 256] + b[c + 256];
    xb[row * DD + c] = y0;
    xb[row * DD + c + 256] = y1;
    xb16[row * DD + c] = f2b(y0);
    xb16[row * DD + c + 256] = f2b(y1);
}

// ---------------- LN3 + FiLM (ffn in bf16) ---------------------------------
__global__ __launch_bounds__(256) void ln3_film_kernel(
    const float* __restrict__ xb, const unsigned short* __restrict__ ffn,
    const int* __restrict__ mode, const float* __restrict__ w,
    const float* __restrict__ b, const float* __restrict__ msc,
    const float* __restrict__ msh, float* __restrict__ out)
{
    __shared__ float red[4];
    size_t row = blockIdx.x;
    int c = threadIdx.x;
    int md = mode[row];
    float v0 = xb[row * DD + c] + b2f(ffn[row * DD + c]);
    float v1 = xb[row * DD + c + 256] + b2f(ffn[row * DD + c + 256]);
    float mean = block_sum_256(v0 + v1, red) * (1.f / 512.f);
    float d0 = v0 - mean, d1 = v1 - mean;
    float var = block_sum_256(d0 * d0 + d1 * d1, red) * (1.f / 512.f);
    float rstd = rsqrtf(var + 1e-5f);
    float y0 = d0 * rstd * w[c] + b[c];
    float y1 = d1 * rstd * w[c + 256] + b[c + 256];
    float p0 = y0 * msc[(size_t)md * DD + c] + msh[(size_t)md * DD + c];
    float p1 = y1 * msc[(size_t)md * DD + c + 256] + msh[(size_t)md * DD + c + 256];
    out[row * DD + c] = fmaxf(p0, 0.f) + y0;
    out[row * DD + c + 256] = fmaxf(p1, 0.f) + y1;
}

// ---------------- new_rep = concat(past_rep, sample_rep) -------------------
__global__ void newrep_kernel(const float* __restrict__ past, const float* __restrict__ rep,
                              float* __restrict__ out, int total)
{
    int i = blockIdx.x * blockDim.x + threadIdx.x;
    if (i >= total) return;
    out[i] = (i < PP * DD) ? past[i] : rep[i - PP * DD];
}

// ---------------- outer attention v2: 4 queries x 1 head per block ---------
// proj layout: [768][2048] fp32, cols: K=0..511, V=512..1023, Q=1024..1535
__global__ __launch_bounds__(256) void outer_attn_v2_kernel(
    const float* __restrict__ proj, float* __restrict__ ob)
{
    __shared__ float kt[64 * 65];     // K/V tile, row-stride 65 (2-way bank = free)
    __shared__ float qs[4 * 64];
    __shared__ float sc[4][776];
    const int ldk = 2048;
    int qi0 = blockIdx.x * 4;
    int h   = blockIdx.y;
    int t = threadIdx.x;
    int lane = t & 63, w = t >> 6;
    int koff = h * 64, voff = 512 + h * 64, qoff = 1024 + h * 64;
    int limq = PP + qi0 + w;          // this wave's query causal limit
    int lim_max = PP + qi0 + 3;

    qs[w * 64 + lane] = proj[(size_t)(PP + qi0 + w) * ldk + qoff + lane];
    __syncthreads();

    // ---- scores ----
    for (int j0 = 0; j0 <= lim_max; j0 += 64) {
#pragma unroll
        for (int e = 0; e < 16; ++e) {
            int s = t + e * 256;
            int r = s >> 6, c = s & 63;
            kt[r * 65 + c] = proj[(size_t)(j0 + r) * ldk + koff + c];
        }
        __syncthreads();
        const float* qrow = &qs[w * 64];
        const float* krow = &kt[lane * 65];
        float d = 0.f;
#pragma unroll
        for (int kk = 0; kk < 64; ++kk) d += qrow[kk] * krow[kk];
        sc[w][j0 + lane] = d * 0.125f;
        __syncthreads();
    }

    // ---- wave-level softmax over this wave's query ----
    int jend = ((lim_max >> 6) + 1) << 6;     // tiles cover [0, jend)
    float m = NEG_BIG;
    for (int j = lane; j <= limq; j += 64) m = fmaxf(m, sc[w][j]);
#pragma unroll
    for (int d = 32; d > 0; d >>= 1) m = fmaxf(m, __shfl_xor(m, d, 64));
    float ssum = 0.f;
    for (int j = lane; j < jend; j += 64) {
        float p = (j <= limq) ? expf(sc[w][j] - m) : 0.f;
        sc[w][j] = p;
        ssum += p;
    }
#pragma unroll
    for (int d = 32; d > 0; d >>= 1) ssum += __shfl_xor(ssum, d, 64);
    float inv = 1.f / ssum;

    // ---- O = P @ V ----
    float acc = 0.f;                  // output (query=w, dim=lane)
    for (int j0 = 0; j0 <= lim_max; j0 += 64) {
        __syncthreads();              // all waves done with kt
#pragma unroll
        for (int e = 0; e < 16; ++e) {
            int s = t + e * 256;
            int r = s >> 6, c = s & 63;
            kt[r * 65 + c] = proj[(size_t)(j0 + r) * ldk + voff + c];
        }
        __syncthreads();
        const float* prow = sc[w] + j0;
        for (int r = 0; r < 64; ++r) acc += prow[r] * kt[r * 65 + lane];
    }
    ob[(size_t)(qi0 + w) * DD + h * 64 + lane] = acc * inv;
}

// ---------------- score attention v2: u4[qi][h] = softmax diag -------------
// proj cols: K2=1536..1791, Q2=1792..2047
__global__ __launch_bounds__(256) void score_attn_v2_kernel(
    const float* __restrict__ proj, float* __restrict__ u4)
{
    __shared__ float kt[64 * 65];
    __shared__ float qs[4 * 64];
    __shared__ float sc[4][776];
    const int ldk = 2048;
    int qi0 = blockIdx.x * 4;
    int h   = blockIdx.y;
    int t = threadIdx.x;
    int lane = t & 63, w = t >> 6;
    int koff = 1536 + h * 64, qoff = 1792 + h * 64;
    int limq = PP + qi0 + w;
    int lim_max = PP + qi0 + 3;

    qs[w * 64 + lane] = proj[(size_t)(PP + qi0 + w) * ldk + qoff + lane];
    __syncthreads();

    for (int j0 = 0; j0 <= lim_max; j0 += 64) {
#pragma unroll
        for (int e = 0; e < 16; ++e) {
            int s = t + e * 256;
            int r = s >> 6, c = s & 63;
            kt[r * 65 + c] = proj[(size_t)(j0 + r) * ldk + koff + c];
        }
        __syncthreads();
        const float* qrow = &qs[w * 64];
        const float* krow = &kt[lane * 65];
        float d = 0.f;
#pragma unroll
        for (int kk = 0; kk < 64; ++kk) d += qrow[kk] * krow[kk];
        sc[w][j0 + lane] = d * 0.125f;
        __syncthreads();
    }

    float m = NEG_BIG;
    for (int j = lane; j <= limq; j += 64) m = fmaxf(m, sc[w][j]);
#pragma unroll
    for (int d = 32; d > 0; d >>= 1) m = fmaxf(m, __shfl_xor(m, d, 64));
    float ssum = 0.f;
    for (int j = lane; j <= limq; j += 64) ssum += expf(sc[w][j] - m);
#pragma unroll
    for (int d = 32; d > 0; d >>= 1) ssum += __shfl_xor(ssum, d, 64);
    if (lane == 0)
        u4[(size_t)(qi0 + w) * 4 + h] = expf(sc[w][limq] - m) / ssum;
}

// ---------------- cumprod finalize (head-mean + reversed cumprod) ----------
__global__ void finalize_kernel(const float* __restrict__ u4, float* __restrict__ out_past,
                                float* __restrict__ out_us, int E)
{
    if (threadIdx.x == 0 && blockIdx.x == 0) {
        float uE = 0.25f * (u4[(E - 1) * 4] + u4[(E - 1) * 4 + 1] + u4[(E - 1) * 4 + 2] + u4[(E - 1) * 4 + 3]);
        out_us[E - 1] = uE;
        float pf = 1.f;
        for (int i = E - 1; i >= 0; --i) {
            float u = 0.25f * (u4[i * 4] + u4[i * 4 + 1] + u4[i * 4 + 2] + u4[i * 4 + 3]);
            if (i < E - 1) out_us[i] = u * pf;
            pf = (1.f - u) * pf;
        }
        out_past[0] = pf;
    }
}

// ---------------------------------------------------------------------------
extern "C" void kernel_launch(void* const* d_in, const int* in_sizes, int n_in,
                              void* d_out, int out_size, void* d_ws, size_t ws_size,
                              hipStream_t stream)
{
    const float* x    = (const float*)d_in[0];
    const float* past = (const float*)d_in[1];
    const int*   lens = (const int*)d_in[2];
    const int*   mode = (const int*)d_in[3];
    const float* t1w1 = (const float*)d_in[4];
    const float* t1b1 = (const float*)d_in[5];
    const float* t1w2 = (const float*)d_in[6];
    const float* t1b2 = (const float*)d_in[7];
    const float* t2w1 = (const float*)d_in[8];
    const float* t2b1 = (const float*)d_in[9];
    const float* t2w2 = (const float*)d_in[10];
    const float* t2b2 = (const float*)d_in[11];
    const float* oq_w = (const float*)d_in[12];
    const float* oq_b = (const float*)d_in[13];
    const float* ok_w = (const float*)d_in[14];
    const float* ok_b = (const float*)d_in[15];
    const float* ov_w = (const float*)d_in[16];
    const float* ov_b = (const float*)d_in[17];
    const float* oo_w = (const float*)d_in[18];
    const float* oo_b = (const float*)d_in[19];
    const float* sq_w = (const float*)d_in[20];
    const float* sq_b = (const float*)d_in[21];
    const float* sk_w = (const float*)d_in[22];
    const float* sk_b = (const float*)d_in[23];
    const float* f1w  = (const float*)d_in[24];
    const float* f1b  = (const float*)d_in[25];
    const float* f2w  = (const float*)d_in[26];
    const float* f2b_ = (const float*)d_in[27];
    const float* ln1w = (const float*)d_in[28];
    const float* ln1b = (const float*)d_in[29];
    const float* ln2w = (const float*)d_in[30];
    const float* ln2b = (const float*)d_in[31];
    const float* ln3w = (const float*)d_in[32];
    const float* ln3b = (const float*)d_in[33];
    const float* msc  = (const float*)d_in[34];
    const float* msh  = (const float*)d_in[35];

    int N  = in_sizes[0] / DD;
    int E  = in_sizes[2];
    int PE = PP + E;
    if (N <= 0) return;

    float* out        = (float*)d_out;
    float* out_x      = out;
    float* out_past   = out + (size_t)N * DD;
    float* out_us     = out_past + 1;
    float* out_newrep = out_us + E;

    // ---- workspace layout ----
    const int CH = 16384;                               // FFN row-chunk
    char* wp = (char*)d_ws;
    unsigned short* b16_a = (unsigned short*)wp;  wp += (size_t)N * DD * 2;
    unsigned short* b16_b = (unsigned short*)wp;  wp += (size_t)N * DD * 2;
    unsigned short* ffh   = (unsigned short*)wp;  wp += (size_t)CH * FF * 2;
    unsigned short* wt1   = (unsigned short*)wp;  wp += (size_t)DD * DD * 2;
    unsigned short* wt2   = (unsigned short*)wp;  wp += (size_t)DD * DD * 2;
    unsigned short* wt3   = (unsigned short*)wp;  wp += (size_t)DD * DD * 2;
    unsigned short* wtf1  = (unsigned short*)wp;  wp += (size_t)FF * DD * 2;
    unsigned short* wtf2  = (unsigned short*)wp;  wp += (size_t)DD * FF * 2;
    unsigned short* wtcat = (unsigned short*)wp;  wp += (size_t)2048 * DD * 2;  // [2048][512]
    unsigned short* nr16  = (unsigned short*)wp;  wp += (size_t)PE * DD * 2;
    float* bcat = (float*)wp;  wp += 2048 * 4;
    float* proj = (float*)wp;  wp += (size_t)PE * 2048 * 4;   // fused projections
    float* sbuf = (float*)wp;  wp += (size_t)N * 4;
    float* wgt  = (float*)wp;  wp += (size_t)N * 4;
    float* rep  = (float*)wp;  wp += (size_t)E * DD * 4;
    float* ob   = (float*)wp;  wp += (size_t)E * DD * 4;
    float* oprj = (float*)wp;  wp += (size_t)E * DD * 4;
    float* u4   = (float*)wp;  wp += (size_t)E * 4 * 4;
    int*   seg  = (int*)wp;    wp += (size_t)N * 4;
    int*   offs = (int*)wp;

    int mg128 = (N + 127) / 128;

    // ---- weight prep: transposes to [N,K] bf16 + fused-projection concat ----
    transpose_b16_kernel<<<dim3(DD / 32, DD / 32), 256, 0, stream>>>(t1w1, wt1, DD, DD);
    transpose_b16_kernel<<<dim3(DD / 32, DD / 32), 256, 0, stream>>>(t1w2, wt2, DD, DD);
    transpose_b16_kernel<<<dim3(DD / 32, DD / 32), 256, 0, stream>>>(t2w1, wt3, DD, DD);
    transpose_b16_kernel<<<dim3(FF / 32, DD / 32), 256, 0, stream>>>(f1w, wtf1, DD, FF);
    transpose_b16_kernel<<<dim3(DD / 32, FF / 32), 256, 0, stream>>>(f2w, wtf2, FF, DD);
    transpose_b16_kernel<<<dim3(DD / 32, DD / 32), 256, 0, stream>>>(ok_w, wtcat,              DD, DD);
    transpose_b16_kernel<<<dim3(DD / 32, DD / 32), 256, 0, stream>>>(ov_w, wtcat + 512 * DD,  DD, DD);
    transpose_b16_kernel<<<dim3(DD / 32, DD / 32), 256, 0, stream>>>(oq_w, wtcat + 1024 * DD, DD, DD);
    transpose_b16_kernel<<<dim3(256 / 32, DD / 32), 256, 0, stream>>>(sk_w, wtcat + 1536 * DD, DD, 256);
    transpose_b16_kernel<<<dim3(256 / 32, DD / 32), 256, 0, stream>>>(sq_w, wtcat + 1792 * DD, DD, 256);
    bcat_kernel<<<8, 256, 0, stream>>>(ok_b, ov_b, oq_b, sk_b, sq_b, bcat);

    // ---- x -> bf16 ----
    size_t n4 = (size_t)N * DD / 4;
    cvt_b16_kernel<<<(int)((n4 + 255) / 256), 256, 0, stream>>>(x, b16_a, n4);

    // ---- inner attention MLPs (bf16 MFMA) ----
    gemm_bf16_kernel<1, 1><<<dim3(mg128, DD / 128), 256, 0, stream>>>(b16_a, wt1, t1b1, b16_b, N, DD, DD);
    gemm_bf16_kernel<1, 0><<<dim3(mg128, DD / 128), 256, 0, stream>>>(b16_b, wt2, t1b2, b16_a, N, DD, DD);
    gemm_bf16_kernel<1, 1><<<dim3(mg128, DD / 128), 256, 0, stream>>>(b16_a, wt3, t2b1, b16_b, N, DD, DD);
    rowdot512_b16_kernel<<<N, 64, 0, stream>>>(b16_b, t2w2, t2b2, sbuf);

    // ---- segment softmax + rep + LN1 ----
    seg_offsets_kernel<<<1, 64, 0, stream>>>(lens, offs, E);
    fill_seg_kernel<<<E, 256, 0, stream>>>(offs, seg);
    seg_softmax_kernel<<<E, 384, 0, stream>>>(sbuf, offs, wgt);
    seg_wsum_kernel<<<E, 256, 0, stream>>>(b16_a, wgt, offs, rep);
    ln1_kernel<<<N, 256, 0, stream>>>(x, b16_a, wgt, ln1w, ln1b, out_x);

    // ---- new_rep output + bf16 copy ----
    int nr_total = PE * DD;
    newrep_kernel<<<(nr_total + 255) / 256, 256, 0, stream>>>(past, rep, out_newrep, nr_total);
    cvt_b16_kernel<<<(nr_total / 4 + 255) / 256, 256, 0, stream>>>(out_newrep, nr16, nr_total / 4);

    // ---- fused K|V|Q|K2|Q2 projection (one MFMA GEMM, N=2048) ----
    gemm_bf16_kernel<0, 0><<<dim3(PE / 128, 2048 / 128), 256, 0, stream>>>(nr16, wtcat, bcat, proj, PE, 2048, DD);

    // ---- outer attention + o-proj + LN2 ----
    outer_attn_v2_kernel<<<dim3(E / 4, 8), 256, 0, stream>>>(proj, ob);
    gemm_kernel<<<dim3(E / 64, DD / 64), 256, 0, stream>>>(ob, oo_w, oo_b, oprj, E, DD, DD, 0);
    ln2_kernel<<<N, 256, 0, stream>>>(out_x, oprj, seg, ln2w, ln2b, b16_b);

    // ---- score attention + finalize ----
    score_attn_v2_kernel<<<dim3(E / 4, 4), 256, 0, stream>>>(proj, u4);
    finalize_kernel<<<1, 64, 0, stream>>>(u4, out_past, out_us, E);

    // ---- FFN (bf16 MFMA, chunked) ----
    for (int r0 = 0; r0 < N; r0 += CH) {
        int mr = N - r0; if (mr > CH) mr = CH;
        int mgc = (mr + 127) / 128;
        gemm_bf16_kernel<1, 1><<<dim3(mgc, FF / 128), 256, 0, stream>>>(
            b16_b + (size_t)r0 * DD, wtf1, f1b, ffh, mr, FF, DD);
        gemm_bf16_kernel<1, 0><<<dim3(mgc, DD / 128), 256, 0, stream>>>(
            ffh, wtf2, f2b_, b16_a + (size_t)r0 * DD, mr, DD, FF);
    }
    ln3_film_kernel<<<N, 256, 0, stream>>>(out_x, b16_a, mode, ln3w, ln3b, msc, msh, out_x);
}